// Round 1
// baseline (226.508 us; speedup 1.0000x reference)
//
#include <hip/hip_runtime.h>
#include <hip/hip_bf16.h>

#define CIN 256
#define CRED 64
#define NB 4
#define NN 4096
#define NSPLIT 4

typedef float v4f __attribute__((ext_vector_type(4)));
typedef short v8s __attribute__((ext_vector_type(8)));
typedef unsigned short u16;
typedef u16 u16x4 __attribute__((ext_vector_type(4)));
typedef unsigned int u32;

__device__ __forceinline__ u16 f2bf(float f) {
    union { float f; u32 u; } v; v.f = f;
    u32 r = (v.u + 0x7FFFu + ((v.u >> 16) & 1u)) >> 16;  // RNE
    return (u16)r;
}
__device__ __forceinline__ float bf2f(u16 s) {
    union { u32 u; float f; } v; v.u = ((u32)s) << 16;
    return v.f;
}
__device__ __forceinline__ v4f mfma16(v8s a, v8s b, v4f c) {
    return __builtin_amdgcn_mfma_f32_16x16x32_bf16(a, b, c, 0, 0, 0);
}

// ---------------- kernel 0: transpose Wq/Wk/Wv (r,c)->(c,r) fp32 -------------
__global__ __launch_bounds__(256) void k_wtrans(const float* __restrict__ Wq,
                                                const float* __restrict__ Wk,
                                                const float* __restrict__ Wv,
                                                float* __restrict__ WT) {
    __shared__ float tile[64][65];
    int w = blockIdx.x >> 2;
    int c0 = (blockIdx.x & 3) * 64;
    const float* W = (w == 0) ? Wq : (w == 1) ? Wk : Wv;
    int t = threadIdx.x;
#pragma unroll
    for (int i = 0; i < 16; ++i) {
        int f = t + i * 256;
        int r = f >> 6, c = f & 63;
        tile[c][r] = W[r * 256 + c0 + c];
    }
    __syncthreads();
#pragma unroll
    for (int i = 0; i < 16; ++i) {
        int f = t + i * 256;
        int cc = f >> 6, r = f & 63;
        WT[w * (CIN * CRED) + (c0 + cc) * 64 + r] = tile[cc][r];
    }
}

// ---------------- kernel 1: QKV projection (fp32 acc, bf16 out) --------------
// Q: (b,n,r) bf16 (scale 0.125 folded in), K: (b,n,r), V: (b,r,n)
__global__ __launch_bounds__(256) void k_qkv(const float* __restrict__ x,
                                             const float* __restrict__ WT,
                                             u16* __restrict__ Q, u16* __restrict__ K,
                                             u16* __restrict__ V) {
    __shared__ float xs[CIN][68];   // pitch 68: 16B-aligned rows, broadcast reads
    int t = threadIdx.x;
    int b = blockIdx.x >> 6;
    int n0 = (blockIdx.x & 63) * 64;
    const float* xb = x + (size_t)b * CIN * NN + n0;
#pragma unroll
    for (int i = 0; i < 16; ++i) {
        int f = t * 4 + i * 1024;
        int c = f >> 6, col = f & 63;
        float4 val = *(const float4*)&xb[(size_t)c * NN + col];
        *(float4*)&xs[c][col] = val;
    }
    __syncthreads();
    int r = t & 63, ng = t >> 6;
    float aq[16], ak[16], av[16];
#pragma unroll
    for (int i = 0; i < 16; ++i) { aq[i] = 0.f; ak[i] = 0.f; av[i] = 0.f; }
#pragma unroll 4
    for (int c = 0; c < CIN; ++c) {
        float wq = WT[c * 64 + r];
        float wk = WT[CIN * CRED + c * 64 + r];
        float wv = WT[2 * CIN * CRED + c * 64 + r];
        float xv[16];
#pragma unroll
        for (int k4 = 0; k4 < 4; ++k4) {
            float4 v4 = *(const float4*)&xs[c][ng * 16 + k4 * 4];
            xv[k4 * 4 + 0] = v4.x; xv[k4 * 4 + 1] = v4.y;
            xv[k4 * 4 + 2] = v4.z; xv[k4 * 4 + 3] = v4.w;
        }
#pragma unroll
        for (int i = 0; i < 16; ++i) {
            aq[i] = fmaf(wq, xv[i], aq[i]);
            ak[i] = fmaf(wk, xv[i], ak[i]);
            av[i] = fmaf(wv, xv[i], av[i]);
        }
    }
    size_t nbase = (size_t)b * NN + n0 + ng * 16;
#pragma unroll
    for (int i = 0; i < 16; ++i) {
        Q[(nbase + i) * 64 + r] = f2bf(aq[i] * 0.125f);  // softmax scale folded
        K[(nbase + i) * 64 + r] = f2bf(ak[i]);
    }
    size_t vbase = ((size_t)b * 64 + r) * NN + n0 + ng * 16;
#pragma unroll
    for (int k4 = 0; k4 < 4; ++k4) {
        u16x4 pk;
#pragma unroll
        for (int j = 0; j < 4; ++j) pk[j] = f2bf(av[k4 * 4 + j]);
        *(u16x4*)&V[vbase + k4 * 4] = pk;
    }
}

// ---------------- kernel 2: flash attention, split-m=4 -----------------------
__global__ __launch_bounds__(256, 2) void k_flash(const u16* __restrict__ Q,
                                                  const u16* __restrict__ K,
                                                  const u16* __restrict__ V,
                                                  u16* __restrict__ OP,
                                                  float* __restrict__ Mb,
                                                  float* __restrict__ Lb) {
    __shared__ u16 Kl[64][72];       // K tile (m,r), pad 72 -> 2-way banks on b128
    __shared__ u16 Vl[64][72];       // V tile (r,m)
    __shared__ u16 Pl[4][32][72];    // per-wave P round-trip (C-layout -> A-layout)
    int t = threadIdx.x;
    int p = blockIdx.x & 3;
    int tile = blockIdx.x >> 2;
    int b = tile >> 5;
    int n0 = (tile & 31) * 128;
    int wv = t >> 6;
    int lane = t & 63;
    int c15 = lane & 15;
    int quad = lane >> 4;
    int nw = n0 + wv * 32;           // this wave's 32 query rows
    const u16* Qb = Q + (size_t)b * NN * 64;
    const u16* Kb = K + (size_t)b * NN * 64;
    const u16* Vb = V + (size_t)b * 64 * NN;

    // A-fragments of Q: A[m=lane&15][k=quad*8+j], k-chunks of 32 over r=64
    v8s Qa[2][2];
#pragma unroll
    for (int rg = 0; rg < 2; ++rg)
#pragma unroll
        for (int c2 = 0; c2 < 2; ++c2)
            Qa[rg][c2] = *(const v8s*)&Qb[(size_t)(nw + rg * 16 + c15) * 64 + c2 * 32 + quad * 8];

    v4f O[2][4];
    float mi[2][4], li[2][4];
#pragma unroll
    for (int rg = 0; rg < 2; ++rg)
#pragma unroll
        for (int g = 0; g < 4; ++g) {
            mi[rg][g] = -1e30f; li[rg][g] = 0.f;
#pragma unroll
            for (int cg = 0; cg < 4; ++cg) O[rg][cg][g] = 0.f;
        }

    int m0 = p * (NN / NSPLIT);
    for (int it = 0; it < (NN / NSPLIT) / 64; ++it) {
        int mt = m0 + it * 64;
        int srow = t >> 3, scol = (t & 7) * 8;
#pragma unroll
        for (int pass = 0; pass < 2; ++pass) {
            int rr = srow + pass * 32;
            *(v8s*)&Kl[rr][scol] = *(const v8s*)&Kb[(size_t)(mt + rr) * 64 + scol];
            *(v8s*)&Vl[rr][scol] = *(const v8s*)&Vb[(size_t)rr * NN + mt + scol];
        }
        __syncthreads();

        // S = Q K^T (scale pre-folded). B-frag: B[k=r][col=m] from Kl[m][r]
        v4f S[2][4];
#pragma unroll
        for (int rg = 0; rg < 2; ++rg)
#pragma unroll
            for (int s = 0; s < 4; ++s)
#pragma unroll
                for (int g = 0; g < 4; ++g) S[rg][s][g] = 0.f;
#pragma unroll
        for (int s = 0; s < 4; ++s)
#pragma unroll
            for (int c2 = 0; c2 < 2; ++c2) {
                v8s kb = *(const v8s*)&Kl[s * 16 + c15][c2 * 32 + quad * 8];
                S[0][s] = mfma16(Qa[0][c2], kb, S[0][s]);
                S[1][s] = mfma16(Qa[1][c2], kb, S[1][s]);
            }

        // online softmax; C-layout: row = quad*4+g, col = s*16 + c15
#pragma unroll
        for (int rg = 0; rg < 2; ++rg) {
            float rmax[4], alpha[4], rsum[4];
#pragma unroll
            for (int g = 0; g < 4; ++g)
                rmax[g] = fmaxf(fmaxf(S[rg][0][g], S[rg][1][g]), fmaxf(S[rg][2][g], S[rg][3][g]));
#pragma unroll
            for (int off = 1; off <= 8; off <<= 1)
#pragma unroll
                for (int g = 0; g < 4; ++g)
                    rmax[g] = fmaxf(rmax[g], __shfl_xor(rmax[g], off));
#pragma unroll
            for (int g = 0; g < 4; ++g) {
                float mn = fmaxf(mi[rg][g], rmax[g]);
                alpha[g] = __expf(mi[rg][g] - mn);
                mi[rg][g] = mn;
            }
#pragma unroll
            for (int s = 0; s < 4; ++s)
#pragma unroll
                for (int g = 0; g < 4; ++g)
                    S[rg][s][g] = __expf(S[rg][s][g] - mi[rg][g]);
#pragma unroll
            for (int g = 0; g < 4; ++g)
                rsum[g] = (S[rg][0][g] + S[rg][1][g]) + (S[rg][2][g] + S[rg][3][g]);
#pragma unroll
            for (int off = 1; off <= 8; off <<= 1)
#pragma unroll
                for (int g = 0; g < 4; ++g)
                    rsum[g] += __shfl_xor(rsum[g], off);
#pragma unroll
            for (int g = 0; g < 4; ++g)
                li[rg][g] = li[rg][g] * alpha[g] + rsum[g];
#pragma unroll
            for (int cg = 0; cg < 4; ++cg)
#pragma unroll
                for (int g = 0; g < 4; ++g) O[rg][cg][g] *= alpha[g];
            // write P (C-layout scatter, bf16)
#pragma unroll
            for (int s = 0; s < 4; ++s)
#pragma unroll
                for (int g = 0; g < 4; ++g)
                    Pl[wv][rg * 16 + quad * 4 + g][s * 16 + c15] = f2bf(S[rg][s][g]);
        }
        __syncthreads();

        // O += P V ; A-frag of P from LDS, B-frag: B[k=m][col=r] from Vl[r][m]
        v8s Pa[2][2];
#pragma unroll
        for (int rg = 0; rg < 2; ++rg)
#pragma unroll
            for (int c2 = 0; c2 < 2; ++c2)
                Pa[rg][c2] = *(const v8s*)&Pl[wv][rg * 16 + c15][c2 * 32 + quad * 8];
#pragma unroll
        for (int cg = 0; cg < 4; ++cg)
#pragma unroll
            for (int c2 = 0; c2 < 2; ++c2) {
                v8s vb = *(const v8s*)&Vl[cg * 16 + c15][c2 * 32 + quad * 8];
                O[0][cg] = mfma16(Pa[0][c2], vb, O[0][cg]);
                O[1][cg] = mfma16(Pa[1][c2], vb, O[1][cg]);
            }
        __syncthreads();
    }

    // epilogue: unnormalized O (bf16) + m,l per row
    u16* OPp = OP + (size_t)p * (NB * NN * 64) + (size_t)b * NN * 64;
#pragma unroll
    for (int rg = 0; rg < 2; ++rg)
#pragma unroll
        for (int cg = 0; cg < 4; ++cg)
#pragma unroll
            for (int g = 0; g < 4; ++g) {
                int n = nw + rg * 16 + quad * 4 + g;
                OPp[(size_t)n * 64 + cg * 16 + c15] = f2bf(O[rg][cg][g]);
            }
    if (c15 == 0) {
        float* Mp = Mb + (size_t)p * (NB * NN) + (size_t)b * NN;
        float* Lp = Lb + (size_t)p * (NB * NN) + (size_t)b * NN;
#pragma unroll
        for (int rg = 0; rg < 2; ++rg)
#pragma unroll
            for (int g = 0; g < 4; ++g) {
                int n = nw + rg * 16 + quad * 4 + g;
                Mp[n] = mi[rg][g];
                Lp[n] = li[rg][g];
            }
    }
}

// ---------------- kernel 3: merge splits + Wp projection + residual ----------
__global__ __launch_bounds__(256) void k_proj(const u16* __restrict__ OP,
                                              const float* __restrict__ Mb,
                                              const float* __restrict__ Lb,
                                              const float* __restrict__ Wp,
                                              const float* __restrict__ x,
                                              float* __restrict__ out) {
    __shared__ float Ol[64 * 65];   // pitch 65 -> 2-way banks for lane-indexed reads
    int t = threadIdx.x;
    int b = blockIdx.x >> 6;
    int n0 = (blockIdx.x & 63) * 64;
#pragma unroll
    for (int i = 0; i < 4; ++i) {
        int f = t * 4 + i * 1024;
        int row = f >> 6, col = f & 63;
        size_t nidx = (size_t)b * NN + n0 + row;
        float m[NSPLIT], l[NSPLIT];
#pragma unroll
        for (int p = 0; p < NSPLIT; ++p) {
            m[p] = Mb[(size_t)p * (NB * NN) + nidx];
            l[p] = Lb[(size_t)p * (NB * NN) + nidx];
        }
        float ms = fmaxf(fmaxf(m[0], m[1]), fmaxf(m[2], m[3]));
        float wgt[NSPLIT]; float den = 0.f;
#pragma unroll
        for (int p = 0; p < NSPLIT; ++p) { wgt[p] = __expf(m[p] - ms); den += wgt[p] * l[p]; }
        float inv = 1.0f / den;
        float o0 = 0.f, o1 = 0.f, o2 = 0.f, o3 = 0.f;
#pragma unroll
        for (int p = 0; p < NSPLIT; ++p) {
            u16x4 u = *(const u16x4*)&OP[(size_t)p * (NB * NN * 64) + nidx * 64 + col];
            o0 += wgt[p] * bf2f(u[0]); o1 += wgt[p] * bf2f(u[1]);
            o2 += wgt[p] * bf2f(u[2]); o3 += wgt[p] * bf2f(u[3]);
        }
        Ol[row * 65 + col + 0] = o0 * inv;
        Ol[row * 65 + col + 1] = o1 * inv;
        Ol[row * 65 + col + 2] = o2 * inv;
        Ol[row * 65 + col + 3] = o3 * inv;
    }
    __syncthreads();
    int n = t & 63;
    int cg = __builtin_amdgcn_readfirstlane(t >> 6);   // wave-uniform c-group
    float ov[64];
#pragma unroll
    for (int rr = 0; rr < 64; ++rr) ov[rr] = Ol[n * 65 + rr];
    const float* xb = x + ((size_t)b * CIN + cg * 64) * NN + n0;
    float* ob = out + ((size_t)b * CIN + cg * 64) * NN + n0;
    for (int j = 0; j < 64; ++j) {
        const float* wpc = Wp + (cg * 64 + j) * 64;    // uniform -> s_loads
        float s0 = 0.f, s1 = 0.f, s2 = 0.f, s3 = 0.f;
#pragma unroll
        for (int rr = 0; rr < 64; rr += 4) {
            s0 = fmaf(wpc[rr], ov[rr], s0);
            s1 = fmaf(wpc[rr + 1], ov[rr + 1], s1);
            s2 = fmaf(wpc[rr + 2], ov[rr + 2], s2);
            s3 = fmaf(wpc[rr + 3], ov[rr + 3], s3);
        }
        float sum = (s0 + s1) + (s2 + s3);
        ob[(size_t)j * NN + n] = sum + xb[(size_t)j * NN + n];
    }
}

extern "C" void kernel_launch(void* const* d_in, const int* in_sizes, int n_in,
                              void* d_out, int out_size, void* d_ws, size_t ws_size,
                              hipStream_t stream) {
    const float* x  = (const float*)d_in[0];
    const float* Wq = (const float*)d_in[1];
    const float* Wk = (const float*)d_in[2];
    const float* Wv = (const float*)d_in[3];
    const float* Wp = (const float*)d_in[4];
    float* out = (float*)d_out;
    char* ws = (char*)d_ws;
    // workspace layout (bytes)
    float* WT = (float*)(ws);                                  // 196608
    u16* Q  = (u16*)(ws + 262144);                             // 2 MB
    u16* K  = (u16*)(ws + 262144 + 2097152);                   // 2 MB
    u16* V  = (u16*)(ws + 262144 + 2 * 2097152);               // 2 MB
    u16* OP = (u16*)(ws + 262144 + 3 * 2097152);               // 8 MB
    float* Mbuf = (float*)(ws + 262144 + 3 * 2097152 + 8388608);       // 256 KB
    float* Lbuf = (float*)(ws + 262144 + 3 * 2097152 + 8388608 + 262144); // 256 KB

    k_wtrans<<<12, 256, 0, stream>>>(Wq, Wk, Wv, WT);
    k_qkv<<<256, 256, 0, stream>>>(x, WT, Q, K, V);
    k_flash<<<512, 256, 0, stream>>>(Q, K, V, OP, Mbuf, Lbuf);
    k_proj<<<256, 256, 0, stream>>>(OP, Mbuf, Lbuf, Wp, x, out);
}